// Round 4
// baseline (818.386 us; speedup 1.0000x reference)
//
#include <hip/hip_runtime.h>

#define S_TOK 16384   // S*N tokens
#define D_DIM 1024
#define F_DIM 4096
#define E_NUM 8

#define BM 256
#define BN 256
#define MT_MAX 72     // sum_e ceil(cnt_e/256) <= 64 + 8 = 72

typedef short bf16x8 __attribute__((ext_vector_type(8)));
typedef float f32x4 __attribute__((ext_vector_type(4)));
typedef unsigned short ushort_t;

static __device__ __forceinline__ unsigned short f32_bf16(float f) {
  unsigned u = __float_as_uint(f);
  return (unsigned short)((u + 0x7FFFu + ((u >> 16) & 1u)) >> 16);
}

static __device__ __forceinline__ unsigned int pack_bf16x2(float a, float b) {
  unsigned ua = __float_as_uint(a);
  unsigned ub = __float_as_uint(b);
  unsigned lo = (ua + 0x7FFFu + ((ua >> 16) & 1u)) >> 16;
  unsigned hi = (ub + 0x7FFFu + ((ub >> 16) & 1u)) & 0xFFFF0000u;
  return lo | hi;
}

static __device__ __forceinline__ uint2 cvt_f4_bf4(const float4 v) {
  uint2 r;
  r.x = pack_bf16x2(v.x, v.y);
  r.y = pack_bf16x2(v.z, v.w);
  return r;
}

static __device__ __forceinline__ void load_lds16(const void* g, void* l) {
  __builtin_amdgcn_global_load_lds(g, l, 16, 0, 0);
}

// ---------------- zero counts ----------------
__global__ void zero_counts_kernel(int* counts) {
  if (threadIdx.x < E_NUM) counts[threadIdx.x] = 0;
}

// ---------------- fp32 -> bf16 cast of W1 and W2 in one launch ----------------
__global__ void cast2_kernel(const float* __restrict__ w1, ushort_t* __restrict__ o1,
                             const float* __restrict__ w2, ushort_t* __restrict__ o2) {
  const int half = 16384;
  const float* src = (blockIdx.x < half) ? w1 : w2;
  ushort_t* dst = (blockIdx.x < half) ? o1 : o2;
  const int b = (blockIdx.x < half) ? blockIdx.x : (blockIdx.x - half);
  const size_t base = ((size_t)b * blockDim.x + threadIdx.x) * 8;
  const float4 v0 = *(const float4*)(src + base);
  const float4 v1 = *(const float4*)(src + base + 4);
  const uint2 a = cvt_f4_bf4(v0), c = cvt_f4_bf4(v1);
  uint4 w; w.x = a.x; w.y = a.y; w.z = c.x; w.w = c.y;
  *(uint4*)(dst + base) = w;
}

// ---------------- gating (+ x cast to bf16) ----------------
__global__ void gate_kernel(const float* __restrict__ x,
                            const float* __restrict__ Wg,
                            ushort_t* __restrict__ xbf,
                            float* __restrict__ prob,
                            int* __restrict__ counts,
                            int* __restrict__ tok_list) {
  const int wv = threadIdx.x >> 6;
  const int lane = threadIdx.x & 63;
  const int t = blockIdx.x * 4 + wv;
  const float* xr = x + (size_t)t * D_DIM;
  ushort_t* xb = xbf + (size_t)t * D_DIM;

  float acc[E_NUM];
#pragma unroll
  for (int e = 0; e < E_NUM; ++e) acc[e] = 0.0f;

#pragma unroll
  for (int i = 0; i < 4; ++i) {
    const int k = i * 256 + lane * 4;
    const float4 v = *(const float4*)(xr + k);
    *(uint2*)(xb + k) = cvt_f4_bf4(v);
#pragma unroll
    for (int e = 0; e < E_NUM; ++e) {
      const float4 w = *(const float4*)(Wg + e * D_DIM + k);
      acc[e] += v.x * w.x + v.y * w.y + v.z * w.z + v.w * w.w;
    }
  }
#pragma unroll
  for (int e = 0; e < E_NUM; ++e) {
#pragma unroll
    for (int off = 32; off > 0; off >>= 1)
      acc[e] += __shfl_xor(acc[e], off, 64);
  }
  if (lane == 0) {
    float m = acc[0]; int bi = 0;
#pragma unroll
    for (int e = 1; e < E_NUM; ++e) {
      if (acc[e] > m) { m = acc[e]; bi = e; }
    }
    float s = 0.0f;
#pragma unroll
    for (int e = 0; e < E_NUM; ++e) s += expf(acc[e] - m);
    prob[t] = 1.0f / s;             // softmax prob of the argmax logit
    int p = atomicAdd(&counts[bi], 1);
    tok_list[bi * S_TOK + p] = t;
  }
}

// ---------------- tile plan: dense (expert, m0) table, BM=256 ----------------
__global__ void plan_kernel(const int* __restrict__ counts, int* __restrict__ plan) {
  if (threadIdx.x == 0) {
    int t = 0;
    for (int e = 0; e < E_NUM; ++e) {
      const int nt = (counts[e] + BM - 1) / BM;
      for (int i = 0; i < nt; ++i) {
        plan[1 + t] = e;
        plan[1 + MT_MAX + t] = i * BM;
        ++t;
      }
    }
    plan[0] = t;
  }
}

// ---------------- grouped GEMM: 256^2 tile, BK=64, 8-phase counted-vmcnt ----
// LDS per dbuf: A-k0 | A-k1 | B-k0 | B-k1, each 256 rows x 32 el (16 KB).
// Swizzle: within a 64B row, 16B slot s_phys = s_log ^ ((row>>1)&3); applied
// to the global SOURCE at stage time (LDS dest linear) and to ds_read addrs.
// Stage placement (tile t, dbuf cur/nxt):  ph0: A1(t+1)->nxt  ph1: B1(t+1)->nxt
//   ph2: A0(t+2)->cur  ph3: B0(t+2)->cur.  vmcnt(8) at end of ph1 and ph3:
//   12 instrs outstanding there; retiring the oldest 4 = exactly the halves
//   needed by the next two phases. Loads never drain to 0 in the loop.
template <int KDIM, int NDIM, int EPI>
__launch_bounds__(512, 2)
__global__ void ffn_kernel(const ushort_t* __restrict__ A,
                           const ushort_t* __restrict__ B,
                           const float* __restrict__ bias,
                           const float* __restrict__ prob,
                           const int* __restrict__ counts,
                           const int* __restrict__ tok_list,
                           const int* __restrict__ plan,
                           ushort_t* __restrict__ Hout,
                           float* __restrict__ out) {
  constexpr int NT = NDIM / BN;
  constexpr int NWG = NT * MT_MAX;     // % 8 == 0
  constexpr int NK = KDIM / 64;
  const int ntiles = plan[0];
  const int wg = (blockIdx.x & 7) * (NWG >> 3) + (blockIdx.x >> 3);
  const int tile = wg / NT;            // m slow, n fast
  if (tile >= ntiles) return;
  const int n0 = (wg % NT) * BN;
  const int e = plan[1 + tile];
  const int m0 = plan[1 + MT_MAX + tile];
  const int cnt = counts[e];

  __shared__ ushort_t Lds[2 * 4 * 8192];   // 128 KB

  const int tid = threadIdx.x;
  const int lane = tid & 63;
  const int wid = tid >> 6;
  const int wr2 = wid >> 2;            // 0/1 : row half
  const int wc4 = wid & 3;             // 0..3: col quarter
  const int l15 = lane & 15;
  const int l4  = lane >> 4;

  // staging geometry: 512 thr x 16B = one 128-row half-instr; 4 thr/row
  const int srow = tid >> 2;           // 0..127
  const int swel = ((tid & 3) ^ ((srow >> 1) & 3)) * 8;   // swizzled src slot
  const int dstoff = wid * 512;        // wave-uniform LDS base (elements)

  const size_t ebase = (size_t)e * S_TOK;
  const int ra0 = m0 + srow, ra1 = m0 + 128 + srow;
  const int tok0 = (ra0 < cnt) ? tok_list[ebase + ra0] : 0;
  const int tok1 = (ra1 < cnt) ? tok_list[ebase + ra1] : 0;
  const ushort_t* aSrc0 = A + (size_t)tok0 * KDIM + swel;
  const ushort_t* aSrc1 = A + (size_t)tok1 * KDIM + swel;
  const ushort_t* Bebase = B + (size_t)e * NDIM * KDIM;
  const ushort_t* bSrc0 = Bebase + (size_t)(n0 + srow) * KDIM + swel;
  const ushort_t* bSrc1 = Bebase + (size_t)(n0 + 128 + srow) * KDIM + swel;

  // ds-read offsets (elements within one 16KB half), swizzled
  int oA[8], oB[4];
#pragma unroll
  for (int m = 0; m < 8; ++m) {
    const int r = wr2 * 128 + m * 16 + l15;
    oA[m] = r * 32 + ((l4 ^ ((r >> 1) & 3)) * 8);
  }
#pragma unroll
  for (int n = 0; n < 4; ++n) {
    const int r = wc4 * 64 + n * 16 + l15;
    oB[n] = r * 32 + ((l4 ^ ((r >> 1) & 3)) * 8);
  }

  f32x4 acc[8][4];
#pragma unroll
  for (int i = 0; i < 8; ++i)
#pragma unroll
    for (int j = 0; j < 4; ++j)
      acc[i][j] = (f32x4){0.f, 0.f, 0.f, 0.f};

  ushort_t* cur = Lds;
  ushort_t* nxt = Lds + 32768;

  // prologue: A0(0),B0(0),A1(0),B1(0) -> cur; A0(1),B0(1) -> nxt (12 instrs)
  {
    load_lds16(aSrc0, cur + dstoff);
    load_lds16(aSrc1, cur + 4096 + dstoff);
    load_lds16(bSrc0, cur + 16384 + dstoff);
    load_lds16(bSrc1, cur + 16384 + 4096 + dstoff);
    load_lds16(aSrc0 + 32, cur + 8192 + dstoff);
    load_lds16(aSrc1 + 32, cur + 8192 + 4096 + dstoff);
    load_lds16(bSrc0 + 32, cur + 24576 + dstoff);
    load_lds16(bSrc1 + 32, cur + 24576 + 4096 + dstoff);
    const int t1 = (NK > 1) ? 64 : 0;
    load_lds16(aSrc0 + t1, nxt + dstoff);
    load_lds16(aSrc1 + t1, nxt + 4096 + dstoff);
    load_lds16(bSrc0 + t1, nxt + 16384 + dstoff);
    load_lds16(bSrc1 + t1, nxt + 16384 + 4096 + dstoff);
    asm volatile("s_waitcnt vmcnt(8)" ::: "memory");
    __builtin_amdgcn_s_barrier();
  }

  for (int t = 0; t < NK; ++t) {
    const int tt1 = ((t + 1 < NK) ? (t + 1) : (NK - 1)) * 64;
    const int tt2 = ((t + 2 < NK) ? (t + 2) : (NK - 1)) * 64;
    bf16x8 a[4], b[4], a2[4];

    // ---- phase 0: stage A1(t+1)->nxt; read A m0-3 kk0 + B kk0; mfma m0-3
    load_lds16(aSrc0 + tt1 + 32, nxt + 8192 + dstoff);
    load_lds16(aSrc1 + tt1 + 32, nxt + 8192 + 4096 + dstoff);
#pragma unroll
    for (int i = 0; i < 4; ++i) a[i] = *(const bf16x8*)(cur + oA[i]);
#pragma unroll
    for (int n = 0; n < 4; ++n) b[n] = *(const bf16x8*)(cur + 16384 + oB[n]);
    __builtin_amdgcn_s_barrier();
    __builtin_amdgcn_s_setprio(1);
#pragma unroll
    for (int i = 0; i < 4; ++i)
#pragma unroll
      for (int n = 0; n < 4; ++n)
        acc[i][n] = __builtin_amdgcn_mfma_f32_16x16x32_bf16(a[i], b[n], acc[i][n], 0, 0, 0);
    __builtin_amdgcn_s_setprio(0);
    __builtin_amdgcn_s_barrier();

    // ---- phase 1: stage B1(t+1)->nxt; read A m4-7 kk0; mfma m4-7
    load_lds16(bSrc0 + tt1 + 32, nxt + 24576 + dstoff);
    load_lds16(bSrc1 + tt1 + 32, nxt + 24576 + 4096 + dstoff);
#pragma unroll
    for (int i = 0; i < 4; ++i) a2[i] = *(const bf16x8*)(cur + oA[4 + i]);
    __builtin_amdgcn_s_barrier();
    __builtin_amdgcn_s_setprio(1);
#pragma unroll
    for (int i = 0; i < 4; ++i)
#pragma unroll
      for (int n = 0; n < 4; ++n)
        acc[4 + i][n] = __builtin_amdgcn_mfma_f32_16x16x32_bf16(a2[i], b[n], acc[4 + i][n], 0, 0, 0);
    __builtin_amdgcn_s_setprio(0);
    asm volatile("s_waitcnt vmcnt(8)" ::: "memory");
    __builtin_amdgcn_s_barrier();

    // ---- phase 2: stage A0(t+2)->cur; read A m0-3 kk1 + B kk1; mfma m0-3
    load_lds16(aSrc0 + tt2, cur + dstoff);
    load_lds16(aSrc1 + tt2, cur + 4096 + dstoff);
#pragma unroll
    for (int i = 0; i < 4; ++i) a[i] = *(const bf16x8*)(cur + 8192 + oA[i]);
#pragma unroll
    for (int n = 0; n < 4; ++n) b[n] = *(const bf16x8*)(cur + 24576 + oB[n]);
    __builtin_amdgcn_s_barrier();
    __builtin_amdgcn_s_setprio(1);
#pragma unroll
    for (int i = 0; i < 4; ++i)
#pragma unroll
      for (int n = 0; n < 4; ++n)
        acc[i][n] = __builtin_amdgcn_mfma_f32_16x16x32_bf16(a[i], b[n], acc[i][n], 0, 0, 0);
    __builtin_amdgcn_s_setprio(0);
    __builtin_amdgcn_s_barrier();

    // ---- phase 3: stage B0(t+2)->cur; read A m4-7 kk1; mfma m4-7
    load_lds16(bSrc0 + tt2, cur + 16384 + dstoff);
    load_lds16(bSrc1 + tt2, cur + 16384 + 4096 + dstoff);
#pragma unroll
    for (int i = 0; i < 4; ++i) a2[i] = *(const bf16x8*)(cur + 8192 + oA[4 + i]);
    __builtin_amdgcn_s_barrier();
    __builtin_amdgcn_s_setprio(1);
#pragma unroll
    for (int i = 0; i < 4; ++i)
#pragma unroll
      for (int n = 0; n < 4; ++n)
        acc[4 + i][n] = __builtin_amdgcn_mfma_f32_16x16x32_bf16(a2[i], b[n], acc[4 + i][n], 0, 0, 0);
    __builtin_amdgcn_s_setprio(0);
    asm volatile("s_waitcnt vmcnt(8)" ::: "memory");
    __builtin_amdgcn_s_barrier();

    ushort_t* tmp = cur; cur = nxt; nxt = tmp;
  }

  // epilogue
  const float* be = bias + (size_t)e * NDIM;
#pragma unroll
  for (int m = 0; m < 8; ++m) {
#pragma unroll
    for (int r = 0; r < 4; ++r) {
      const int slot = m0 + wr2 * 128 + m * 16 + l4 * 4 + r;
      if (slot >= cnt) continue;
      const int tok = tok_list[ebase + slot];
      if (EPI == 0) {
        ushort_t* hrow = Hout + (size_t)tok * NDIM;
#pragma unroll
        for (int n = 0; n < 4; ++n) {
          const int col = n0 + wc4 * 64 + n * 16 + l15;
          float v = acc[m][n][r] + be[col];
          v = 0.5f * v * (1.0f + erff(v * 0.70710678118654752f));
          hrow[col] = f32_bf16(v);
        }
      } else {
        const float p = prob[tok];
        float* orow = out + (size_t)tok * NDIM;
#pragma unroll
        for (int n = 0; n < 4; ++n) {
          const int col = n0 + wc4 * 64 + n * 16 + l15;
          orow[col] = (acc[m][n][r] + be[col]) * p;
        }
      }
    }
  }
}

extern "C" void kernel_launch(void* const* d_in, const int* in_sizes, int n_in,
                              void* d_out, int out_size, void* d_ws, size_t ws_size,
                              hipStream_t stream) {
  const float* x  = (const float*)d_in[0];
  const float* Wg = (const float*)d_in[1];
  const float* W1 = (const float*)d_in[2];
  const float* b1 = (const float*)d_in[3];
  const float* W2 = (const float*)d_in[4];
  const float* b2 = (const float*)d_in[5];
  float* out = (float*)d_out;

  const size_t MB = 1ull << 20;
  char* ws = (char*)d_ws;
  int* counts      = (int*)(ws);                 // 32 B
  int* plan        = (int*)(ws + 4096);          // ~600 B
  float* prob      = (float*)(ws + 64 * 1024);   // 64 KB
  int* tok_list    = (int*)(ws + 128 * 1024);    // 512 KB
  ushort_t* xbf    = (ushort_t*)(ws + 1 * MB);   // 32 MB
  ushort_t* W1bf   = (ushort_t*)(ws + 33 * MB);  // 64 MB
  ushort_t* W2bf   = (ushort_t*)(ws + 97 * MB);  // 64 MB
  ushort_t* H      = (ushort_t*)(ws + 161 * MB); // 128 MB

  zero_counts_kernel<<<1, 64, 0, stream>>>(counts);
  gate_kernel<<<S_TOK / 4, 256, 0, stream>>>(x, Wg, xbf, prob, counts, tok_list);
  plan_kernel<<<1, 64, 0, stream>>>(counts, plan);

  cast2_kernel<<<32768, 256, 0, stream>>>(W1, W1bf, W2, W2bf);

  ffn_kernel<D_DIM, F_DIM, 0><<<(F_DIM / BN) * MT_MAX, 512, 0, stream>>>(
      xbf, W1bf, b1, nullptr, counts, tok_list, plan, H, nullptr);

  ffn_kernel<F_DIM, D_DIM, 1><<<(D_DIM / BN) * MT_MAX, 512, 0, stream>>>(
      H, W2bf, b2, prob, counts, tok_list, plan, nullptr, out);
}